// Round 8
// baseline (87.634 us; speedup 1.0000x reference)
//
#include <hip/hip_runtime.h>

// UCBNorm, TWO kernels (was 3 - fin folded into k2's preamble; per-node graph
// overhead ~5-10us dominates our budget). No atomics / memset / coop launch /
// grid barrier (r6: agent-scope fences = 197us coherence thrash).
//
// Math (softmax(prior) over size-1 axis == 1 -> constant 1/sqrt(1+EPS)):
//   p_k = exp(qa x^2 + qb x + qc)  (expanded -0.5(x-m)^2/(softplus(v)+EPS))
//   den = EPS + sum_k p,  tau = p/den,  S[k,d] = EPS + sum_{b,t} tau
//   e = (sum_t tau x)/(T S),  var = (sum_t tau^3 x^2)/(T S^3)
//   out = (1/sqrt(1+EPS)) * rden * (x * sum_k p r_k - sum_k p e_k r_k)
//
// k1: 512 blocks (b, 16-d slice, T-half); LDS tree over 16 t-parallel lanes
//     -> partials [2][K][B][D] (768 KB).
// k2: 256 blocks (b, 32-t chunk) x 512 thr; block-redundant finalize of all
//     2048 (k,d) -> LDS (r, e*r); then main loop, factored epilogue.

namespace {
constexpr int K = 8, B = 16, T = 512, D = 256;
constexpr float EPS = 1e-3f;
constexpr int DSL = 16;              // d per slice in k1
constexpr int NSL = D / DSL;         // 16 slices
constexpr int TCH = 2;               // t-chunks in k1
constexpr int TLC = T / TCH;         // 256 t per chunk
constexpr int TP  = 16;              // t-parallel threads
constexpr int RT  = TLC / TP;        // 16 t-iters per thread
constexpr int KS  = 3 * K;           // 24
constexpr int PSZ = TCH * K * B * D; // 65536 floats per partial array
}

__global__ __launch_bounds__(256) void ucb_k1(
    const float* __restrict__ x, const float* __restrict__ mean,
    const float* __restrict__ variance,
    float* __restrict__ pt, float* __restrict__ p1s, float* __restrict__ p3s)
{
  __shared__ float red[TP][DSL][KS + 1];   // 25.6 KB, stride 25

  const int tid = threadIdx.x;
  const int dl  = tid & 15;
  const int tp  = tid >> 4;
  const int bi  = blockIdx.x;
  const int b   = bi >> 5;
  const int sl  = (bi >> 1) & 15;
  const int tch = bi & 1;
  const int dd  = sl*DSL + dl;

  float qa[K], qb[K], qc[K];
#pragma unroll
  for (int k = 0; k < K; ++k) {
    float mk = mean[k*D + dd];
    float sp = log1pf(__expf(variance[k*D + dd]));   // softplus
    float nh = -0.5f / (sp + EPS);
    qa[k] = nh; qb[k] = -2.0f*nh*mk; qc[k] = nh*mk*mk;
  }

  float ast[K], as1[K], as3[K];
#pragma unroll
  for (int k = 0; k < K; ++k) { ast[k]=0.f; as1[k]=0.f; as3[k]=0.f; }

  // t = tch*TLC + tp + TP*j
  const float* xp = x + ((size_t)b*T + (size_t)tch*TLC + tp)*D + dd;
#pragma unroll 4
  for (int j = 0; j < RT; ++j) {
    float xv = xp[(size_t)j*TP*D];
    float x2 = xv*xv;
    float p[K];
#pragma unroll
    for (int k = 0; k < K; ++k)
      p[k] = __expf(fmaf(qa[k], x2, fmaf(qb[k], xv, qc[k])));
    float den = EPS + ((p[0]+p[1])+(p[2]+p[3])) + ((p[4]+p[5])+(p[6]+p[7]));
    float rden = __builtin_amdgcn_rcpf(den);
#pragma unroll
    for (int k = 0; k < K; ++k) {
      float tau = p[k]*rden;
      float tx  = tau*xv;
      ast[k] += tau;
      as1[k] += tx;
      as3[k]  = fmaf(tx*tx, tau, as3[k]);   // tau^3 x^2
    }
  }

#pragma unroll
  for (int k = 0; k < K; ++k) {
    red[tp][dl][3*k+0] = ast[k];
    red[tp][dl][3*k+1] = as1[k];
    red[tp][dl][3*k+2] = as3[k];
  }
  __syncthreads();

#pragma unroll
  for (int i = 0; i < 2; ++i) {            // 384 items
    const int item = tid + i*256;
    if (item < DSL*KS) {
      const int dloc = item / KS;
      const int ks   = item % KS;
      float s = 0.f;
#pragma unroll
      for (int t2 = 0; t2 < TP; ++t2) s += red[t2][dloc][ks];
      const int k = ks / 3, stat = ks % 3;
      const size_t idx = ((size_t)((tch*K + k)*B + b))*D + sl*DSL + dloc;
      if      (stat == 0) pt [idx] = s;
      else if (stat == 1) p1s[idx] = s;
      else                p3s[idx] = s;
    }
  }
}

__global__ __launch_bounds__(512) void ucb_k2(
    const float* __restrict__ x, const float* __restrict__ mean,
    const float* __restrict__ variance,
    const float* __restrict__ pt, const float* __restrict__ p1s,
    const float* __restrict__ p3s, float* __restrict__ out)
{
  __shared__ float rr_l[K][D];     // r              (8 KB)
  __shared__ float erc_l[K][D];    // e*r            (8 KB)

  const int tid = threadIdx.x;
  const int b   = blockIdx.x >> 4;
  const int tc  = blockIdx.x & 15;         // 16 chunks x 32 t

  // ---- block-redundant finalize: 2048 (k,d) items, 4 per thread ----
  const float rT = 1.0f / T;
#pragma unroll
  for (int i = 0; i < 4; ++i) {
    const int item = tid + i*512;
    const int d = item & 255;
    const int k = item >> 8;
    float S = EPS;
#pragma unroll
    for (int tch = 0; tch < TCH; ++tch)
#pragma unroll
      for (int bb = 0; bb < B; ++bb)
        S += pt[((size_t)((tch*K + k)*B + bb))*D + d];
    const size_t i0 = ((size_t)((0*K + k)*B + b))*D + d;
    const size_t i1 = ((size_t)((1*K + k)*B + b))*D + d;
    const float a1 = p1s[i0] + p1s[i1];
    const float a3 = p3s[i0] + p3s[i1];
    const float rS = 1.0f / S;
    const float e  = a1 * rT * rS;
    const float vv = a3 * rT * (rS*rS*rS);
    const float r  = rsqrtf(vv + EPS);
    rr_l[k][d]  = r;
    erc_l[k][d] = e * r;
  }
  __syncthreads();

  // ---- main loop: 32 t per block, thread = (t2, d) ----
  const int d  = tid & 255;
  const int t2 = tid >> 8;                 // 0..1

  float qa[K], qb[K], qc[K], rr[K], erc[K];
#pragma unroll
  for (int k = 0; k < K; ++k) {
    float mk = mean[k*D + d];
    float sp = log1pf(__expf(variance[k*D + d]));
    float nh = -0.5f / (sp + EPS);
    qa[k] = nh; qb[k] = -2.0f*nh*mk; qc[k] = nh*mk*mk;
    rr[k]  = rr_l[k][d];
    erc[k] = erc_l[k][d];
  }

  const float isp = 0.99950037f;           // 1/sqrt(1+EPS)
  // t = tc*32 + j*2 + t2
  const size_t base = ((size_t)b*T + (size_t)tc*32 + t2)*D + d;
#pragma unroll 4
  for (int j = 0; j < 16; ++j) {
    float xv = x[base + (size_t)(j*2)*D];
    float x2 = xv*xv;
    float p[K];
#pragma unroll
    for (int k = 0; k < K; ++k)
      p[k] = __expf(fmaf(qa[k], x2, fmaf(qb[k], xv, qc[k])));
    float den = EPS + ((p[0]+p[1])+(p[2]+p[3])) + ((p[4]+p[5])+(p[6]+p[7]));
    float rden = __builtin_amdgcn_rcpf(den);
    float acc1 = 0.f, acc2 = 0.f;
#pragma unroll
    for (int k = 0; k < K; ++k) {
      acc1 = fmaf(p[k], rr[k],  acc1);     // sum p*r
      acc2 = fmaf(p[k], erc[k], acc2);     // sum p*e*r
    }
    out[base + (size_t)(j*2)*D] = (xv*acc1 - acc2) * rden * isp;
  }
}

extern "C" void kernel_launch(void* const* d_in, const int* in_sizes, int n_in,
                              void* d_out, int out_size, void* d_ws, size_t ws_size,
                              hipStream_t stream) {
  const float* x        = (const float*)d_in[0];
  const float* mean     = (const float*)d_in[1];
  const float* variance = (const float*)d_in[2];
  // d_in[3] (prior): softmax over size-1 axis == 1 -> constant baked in.

  float* out = (float*)d_out;
  float* w   = (float*)d_ws;
  float* pt  = w;            // [TCH][K][B][D] = 65536 floats
  float* p1s = pt  + PSZ;
  float* p3s = p1s + PSZ;
  // every ws element is written before it is read -> no memset needed

  ucb_k1<<<B*NSL*TCH, 256, 0, stream>>>(x, mean, variance, pt, p1s, p3s);
  ucb_k2<<<B*16,      512, 0, stream>>>(x, mean, variance, pt, p1s, p3s, out);
}

// Round 9
// 87.184 us; speedup vs baseline: 1.0052x; 1.0052x over previous
//
#include <hip/hip_runtime.h>

// UCBNorm, 3 kernels (r7 structure - measured best 85.1us; r8's 2-kernel
// fold-in was neutral/worse). This round: k1 wave layout fixed to
// 64-consecutive-d per wave (full 256B coalesced segments; r7's 16dx4tp
// issued half-cacheline fetches shared with other blocks' lines).
//
// Math (softmax(prior) over size-1 axis == 1 -> constant 1/sqrt(1+EPS)):
//   p_k = exp(qa x^2 + qb x + qc)  (expanded -0.5(x-m)^2/(softplus(v)+EPS))
//   den = EPS + sum_k p,  tau = p/den,  S[k,d] = EPS + sum_{b,t} tau
//   e = (sum_t tau x)/(T S),  var = (sum_t tau^3 x^2)/(T S^3)
//   out = (1/sqrt(1+EPS)) * rden * (x * sum_k p r_k - sum_k p e_k r_k)
//
// k1:  256 blocks (b, 64-d slice, T/4 chunk); waves = 64 consecutive d x 4 tp;
//      LDS tree over tp -> partials [4][K][B][D] (512 KB/array).
// fin: 128 blocks; per (k,b,d): 12 coalesced loads; cross-b S via LDS.
// k2:  1024 blocks (b, 8-t chunk) x 256 d; recompute p, factored epilogue.

namespace {
constexpr int K = 8, B = 16, T = 512, D = 256;
constexpr float EPS = 1e-3f;
constexpr int DSL = 64;              // d per slice in k1
constexpr int NSL = D / DSL;         // 4 slices
constexpr int TCH = 4;               // t-chunks in k1
constexpr int TLC = T / TCH;         // 128 t per chunk
constexpr int TP  = 4;               // t-parallel waves
constexpr int RT  = TLC / TP;        // 32 t-iters per thread
constexpr int KS  = 3 * K;           // 24
constexpr int PSZ = TCH * K * B * D; // 131072 floats per partial array
}

__global__ __launch_bounds__(256) void ucb_k1(
    const float* __restrict__ x, const float* __restrict__ mean,
    const float* __restrict__ variance,
    float* __restrict__ pt, float* __restrict__ p1s, float* __restrict__ p3s)
{
  __shared__ float red[TP][DSL][KS + 1];   // 25.6 KB, stride 25

  const int tid = threadIdx.x;
  const int dl  = tid & 63;                // 64 consecutive d per wave
  const int tp  = tid >> 6;                // wave id = t-phase
  const int bi  = blockIdx.x;
  const int b   = bi >> 4;
  const int sl  = (bi >> 2) & 3;
  const int tch = bi & 3;
  const int dd  = sl*DSL + dl;

  float qa[K], qb[K], qc[K];
#pragma unroll
  for (int k = 0; k < K; ++k) {
    float mk = mean[k*D + dd];
    float sp = log1pf(__expf(variance[k*D + dd]));   // softplus
    float nh = -0.5f / (sp + EPS);
    qa[k] = nh; qb[k] = -2.0f*nh*mk; qc[k] = nh*mk*mk;
  }

  float ast[K], as1[K], as3[K];
#pragma unroll
  for (int k = 0; k < K; ++k) { ast[k]=0.f; as1[k]=0.f; as3[k]=0.f; }

  // t = tch*TLC + tp + TP*j
  const float* xp = x + ((size_t)b*T + (size_t)tch*TLC + tp)*D + dd;
#pragma unroll 4
  for (int j = 0; j < RT; ++j) {
    float xv = xp[(size_t)j*TP*D];
    float x2 = xv*xv;
    float p[K];
#pragma unroll
    for (int k = 0; k < K; ++k)
      p[k] = __expf(fmaf(qa[k], x2, fmaf(qb[k], xv, qc[k])));
    float den = EPS + ((p[0]+p[1])+(p[2]+p[3])) + ((p[4]+p[5])+(p[6]+p[7]));
    float rden = __builtin_amdgcn_rcpf(den);
#pragma unroll
    for (int k = 0; k < K; ++k) {
      float tau = p[k]*rden;
      float tx  = tau*xv;
      ast[k] += tau;
      as1[k] += tx;
      as3[k]  = fmaf(tx*tx, tau, as3[k]);   // tau^3 x^2
    }
  }

#pragma unroll
  for (int k = 0; k < K; ++k) {
    red[tp][dl][3*k+0] = ast[k];
    red[tp][dl][3*k+1] = as1[k];
    red[tp][dl][3*k+2] = as3[k];
  }
  __syncthreads();

#pragma unroll
  for (int i = 0; i < 6; ++i) {            // 1536 items; ks wave-uniform
    const int item = tid + i*256;
    const int dloc = item & 63;
    const int ks   = item >> 6;            // 0..23
    float s = red[0][dloc][ks] + red[1][dloc][ks]
            + red[2][dloc][ks] + red[3][dloc][ks];
    const int k = ks / 3, stat = ks % 3;
    const size_t idx = ((size_t)((tch*K + k)*B + b))*D + sl*DSL + dloc;
    if      (stat == 0) pt [idx] = s;
    else if (stat == 1) p1s[idx] = s;
    else                p3s[idx] = s;
  }
}

__global__ __launch_bounds__(256) void ucb_fin(
    const float* __restrict__ pt, const float* __restrict__ p1s,
    const float* __restrict__ p3s, float* __restrict__ er)  // [B][K][2][D]
{
  // 128 blocks: (k, 16-d group); 256 thr = 16 b x 16 d
  __shared__ float reds[B][17];

  const int k  = blockIdx.x >> 4;
  const int d0 = (blockIdx.x & 15) * 16;
  const int dl = threadIdx.x & 15;
  const int bb = threadIdx.x >> 4;
  const int d  = d0 + dl;

  float a0 = 0.f, a1 = 0.f, a3 = 0.f;
#pragma unroll
  for (int tch = 0; tch < TCH; ++tch) {
    const size_t idx = ((size_t)((tch*K + k)*B + bb))*D + d;
    a0 += pt[idx]; a1 += p1s[idx]; a3 += p3s[idx];
  }

  reds[bb][dl] = a0;
  __syncthreads();
  if (threadIdx.x < 16) {
    float s = 0.f;
#pragma unroll
    for (int b2 = 0; b2 < B; ++b2) s += reds[b2][threadIdx.x];
    reds[0][threadIdx.x] = 1.0f / (s + EPS);             // rS
  }
  __syncthreads();

  const float rS = reds[0][dl];
  const float rT = 1.0f / T;
  const float e  = a1 * rT * rS;
  const float vv = a3 * rT * (rS*rS*rS);
  const float r  = rsqrtf(vv + EPS);
  er[((size_t)(bb*K + k)*2 + 0)*D + d] = e;
  er[((size_t)(bb*K + k)*2 + 1)*D + d] = r;
}

__global__ __launch_bounds__(256) void ucb_k2(
    const float* __restrict__ x, const float* __restrict__ mean,
    const float* __restrict__ variance, const float* __restrict__ er,
    float* __restrict__ out)
{
  const int d  = threadIdx.x;
  const int b  = blockIdx.x >> 6;
  const int tc = blockIdx.x & 63;          // 64 chunks x 8 t

  float qa[K], qb[K], qc[K], rr[K], erc[K];
#pragma unroll
  for (int k = 0; k < K; ++k) {
    float mk = mean[k*D + d];
    float sp = log1pf(__expf(variance[k*D + d]));
    float nh = -0.5f / (sp + EPS);
    qa[k] = nh; qb[k] = -2.0f*nh*mk; qc[k] = nh*mk*mk;
    float e = er[((size_t)(b*K + k)*2 + 0)*D + d];
    float r = er[((size_t)(b*K + k)*2 + 1)*D + d];
    rr[k] = r; erc[k] = e*r;
  }

  const float isp = 0.99950037f;           // 1/sqrt(1+EPS)
  const size_t base = ((size_t)b*T + (size_t)tc*8)*D + d;
#pragma unroll
  for (int t = 0; t < 8; ++t) {
    float xv = x[base + (size_t)t*D];
    float x2 = xv*xv;
    float p[K];
#pragma unroll
    for (int k = 0; k < K; ++k)
      p[k] = __expf(fmaf(qa[k], x2, fmaf(qb[k], xv, qc[k])));
    float den = EPS + ((p[0]+p[1])+(p[2]+p[3])) + ((p[4]+p[5])+(p[6]+p[7]));
    float rden = __builtin_amdgcn_rcpf(den);
    float acc1 = 0.f, acc2 = 0.f;
#pragma unroll
    for (int k = 0; k < K; ++k) {
      acc1 = fmaf(p[k], rr[k],  acc1);     // sum p*r
      acc2 = fmaf(p[k], erc[k], acc2);     // sum p*e*r
    }
    out[base + (size_t)t*D] = (xv*acc1 - acc2) * rden * isp;
  }
}

extern "C" void kernel_launch(void* const* d_in, const int* in_sizes, int n_in,
                              void* d_out, int out_size, void* d_ws, size_t ws_size,
                              hipStream_t stream) {
  const float* x        = (const float*)d_in[0];
  const float* mean     = (const float*)d_in[1];
  const float* variance = (const float*)d_in[2];
  // d_in[3] (prior): softmax over size-1 axis == 1 -> constant baked in.

  float* out = (float*)d_out;
  float* w   = (float*)d_ws;
  float* pt  = w;            // [TCH][K][B][D] = 131072 floats
  float* p1s = pt  + PSZ;
  float* p3s = p1s + PSZ;
  float* er  = p3s + PSZ;    // [B][K][2][D] = 65536 floats
  // every ws element is written before it is read -> no memset needed

  ucb_k1 <<<B*NSL*TCH, 256, 0, stream>>>(x, mean, variance, pt, p1s, p3s);
  ucb_fin<<<K*(D/16),  256, 0, stream>>>(pt, p1s, p3s, er);
  ucb_k2 <<<B*64,      256, 0, stream>>>(x, mean, variance, er, out);
}